// Round 4
// baseline (167.062 us; speedup 1.0000x reference)
//
#include <hip/hip_runtime.h>
#include <stdint.h>

// ---------------------------------------------------------------------------
// GeometricAttention: x@Wqkv -> RoPE -> causal MHA -> @Wo -> blade mixing
// B=2 T=2048 N=8 D=128, d_model=1024. bf16 MFMA pipeline, fp32 accum.
// ---------------------------------------------------------------------------

typedef __attribute__((ext_vector_type(8)))  __bf16 bf16x8;
typedef __attribute__((ext_vector_type(4)))  float  f32x4;
typedef __attribute__((ext_vector_type(16))) float  f32x16;

__device__ __forceinline__ uint16_t f2bf(float f) {
    uint32_t u = __float_as_uint(f);
    u += 0x7FFFu + ((u >> 16) & 1u);           // RNE
    return (uint16_t)(u >> 16);
}
__device__ __forceinline__ float bf2f(uint16_t h) {
    return __uint_as_float(((uint32_t)h) << 16);
}

__device__ __forceinline__ void gload_lds16(const void* g, void* l) {
    __builtin_amdgcn_global_load_lds(
        (__attribute__((address_space(1))) void*)g,
        (__attribute__((address_space(3))) void*)l, 16, 0, 0);
}

__device__ __forceinline__ void store_out(uint16_t* p, float v) { *p = f2bf(v); }
__device__ __forceinline__ void store_out(float* p, float v)    { *p = v; }

// ---------------------------------------------------------------- cast fp32->bf16
__global__ __launch_bounds__(256) void k_cast(const float* __restrict__ in,
                                              uint16_t* __restrict__ out, int n) {
    int i = blockIdx.x * 256 + threadIdx.x;          // one float4 per thread
    if (i * 4 >= n) return;
    float4 v = ((const float4*)in)[i];
    ushort4 o = make_ushort4(f2bf(v.x), f2bf(v.y), f2bf(v.z), f2bf(v.w));
    ((ushort4*)out)[i] = o;
}

// ------------------------------------------------- transpose W [K][N] -> Wt [N][K] bf16
__global__ __launch_bounds__(256) void k_wtrans(const float* __restrict__ W,
                                                uint16_t* __restrict__ Wt,
                                                int K, int N) {
    __shared__ uint16_t tile[64][65];
    const int k0 = blockIdx.y * 64, n0 = blockIdx.x * 64;
    const int c = threadIdx.x & 63, r4 = threadIdx.x >> 6;
#pragma unroll
    for (int i = 0; i < 16; ++i) {
        int r = r4 + i * 4;
        tile[r][c] = f2bf(W[(size_t)(k0 + r) * N + n0 + c]);
    }
    __syncthreads();
#pragma unroll
    for (int i = 0; i < 16; ++i) {
        int r = r4 + i * 4;
        Wt[(size_t)(n0 + r) * K + k0 + c] = tile[c][r];
    }
}

// ---------------------------------------------------------------- RoPE tables
__global__ __launch_bounds__(256) void k_tab(float* __restrict__ ct,
                                             float* __restrict__ st) {
    int i = blockIdx.x * 256 + threadIdx.x;          // 2048*64
    int t = i >> 6, f = i & 63;
    float inv = expf(-(float)f * 0.14391156830441f); // ln(10000)/64
    float ang = (float)t * inv;
    ct[i] = cosf(ang);
    st[i] = sinf(ang);
}

// ------------------------------------------------------- m97-style bf16 GEMM
// C[M][N] = A[M][K] * Bt[N][K]^T ; 128x128 tile, BK=32, 4 waves
template <typename OutT>
__global__ __launch_bounds__(256) void k_gemm(const uint16_t* __restrict__ A,
                                              const uint16_t* __restrict__ Bt,
                                              OutT* __restrict__ C,
                                              int M, int N, int K) {
    __shared__ uint16_t Atile[128 * 32];
    __shared__ uint16_t Btile[128 * 32];
    const int m0 = blockIdx.y << 7, n0 = blockIdx.x << 7;
    const int tid = threadIdx.x;
    const int l = tid & 63, w = tid >> 6;
    const int lr = l & 15, lg = l >> 4;
    const int wm = (w >> 1) << 6, wn = (w & 1) << 6;

    f32x4 acc[4][4];
#pragma unroll
    for (int i = 0; i < 4; ++i)
#pragma unroll
        for (int j = 0; j < 4; ++j) acc[i][j] = (f32x4){0.f, 0.f, 0.f, 0.f};

    const int nk = K >> 5;
    for (int kt = 0; kt < nk; ++kt) {
        const int k0 = kt << 5;
        __syncthreads();
#pragma unroll
        for (int c = 0; c < 4; ++c) {
            int idx = c * 256 + tid;                 // 0..1023, wave-contiguous
            if (idx < 512) {
                int r = idx >> 2, kc = (idx & 3) << 3;
                gload_lds16(A + (size_t)(m0 + r) * K + k0 + kc, &Atile[idx * 8]);
            } else {
                int i2 = idx - 512;
                int r = i2 >> 2, kc = (i2 & 3) << 3;
                gload_lds16(Bt + (size_t)(n0 + r) * K + k0 + kc, &Btile[i2 * 8]);
            }
        }
        __syncthreads();
        bf16x8 af[4], bfv[4];
#pragma unroll
        for (int i = 0; i < 4; ++i) {
            af[i]  = *(const bf16x8*)(&Atile[(wm + i * 16 + lr) * 32 + lg * 8]);
            bfv[i] = *(const bf16x8*)(&Btile[(wn + i * 16 + lr) * 32 + lg * 8]);
        }
#pragma unroll
        for (int mi = 0; mi < 4; ++mi)
#pragma unroll
            for (int ni = 0; ni < 4; ++ni)
                acc[mi][ni] = __builtin_amdgcn_mfma_f32_16x16x32_bf16(
                    af[mi], bfv[ni], acc[mi][ni], 0, 0, 0);
    }
    // C/D layout: col = lane&15, row = (lane>>4)*4 + reg   [m89-verified]
#pragma unroll
    for (int mi = 0; mi < 4; ++mi)
#pragma unroll
        for (int ni = 0; ni < 4; ++ni)
#pragma unroll
            for (int r = 0; r < 4; ++r) {
                int row = m0 + wm + mi * 16 + lg * 4 + r;
                int col = n0 + wn + ni * 16 + lr;
                store_out(&C[(size_t)row * N + col], acc[mi][ni][r]);
            }
}

// ------------------------------------------- RoPE apply: QKV -> Q,K [h][T][D]
__global__ __launch_bounds__(256) void k_rope(const uint16_t* __restrict__ qkv,
                                              const float* __restrict__ ct,
                                              const float* __restrict__ st,
                                              uint16_t* __restrict__ Qo,
                                              uint16_t* __restrict__ Ko) {
    int idx = blockIdx.x * 256 + threadIdx.x;        // B*T*N*64 pairs
    int d  = idx & 63;
    int n  = (idx >> 6) & 7;
    int bt = idx >> 9;
    int t  = bt & 2047, b = bt >> 11;
    float c = ct[t * 64 + d], s = st[t * 64 + d];
    size_t base = (size_t)bt * 3072 + n * 128 + d;
    float q1 = bf2f(qkv[base]),        q2 = bf2f(qkv[base + 64]);
    float k1 = bf2f(qkv[base + 1024]), k2 = bf2f(qkv[base + 1024 + 64]);
    size_t ob = ((size_t)(b * 8 + n) * 2048 + t) * 128 + d;
    Qo[ob]      = f2bf(q1 * c - q2 * s);
    Qo[ob + 64] = f2bf(q2 * c + q1 * s);
    Ko[ob]      = f2bf(k1 * c - k2 * s);
    Ko[ob + 64] = f2bf(k2 * c + k1 * s);
}

// -------------------------------------- V transpose: QKV v-part -> Vt [h][D][T]
__global__ __launch_bounds__(256) void k_vtrans(const uint16_t* __restrict__ qkv,
                                                uint16_t* __restrict__ Vt) {
    __shared__ uint16_t tile[64][65];
    const int h = blockIdx.z, b = h >> 3, n = h & 7;
    const int t0 = blockIdx.y * 64, d0 = blockIdx.x * 64;
    const int c = threadIdx.x & 63, r4 = threadIdx.x >> 6;
#pragma unroll
    for (int i = 0; i < 16; ++i) {
        int r = r4 + i * 4;                          // t offset
        tile[r][c] = qkv[(size_t)(b * 2048 + t0 + r) * 3072 + 2048 + n * 128 + d0 + c];
    }
    __syncthreads();
#pragma unroll
    for (int i = 0; i < 16; ++i) {
        int r = r4 + i * 4;                          // d offset
        Vt[((size_t)h * 128 + d0 + r) * 2048 + t0 + c] = tile[c][r];
    }
}

// --------------------------------------------------- causal flash attention
// 32x32x16 MFMA version: 2 waves/block, 32 q-rows per wave (Q in registers as
// B-operand), KV tiles of 64. Each 16KB K/V LDS tile read now serves 32 q-rows
// -> LDS bytes per unit work halved vs the 16x16 variant. P stays entirely in
// registers: C-layout -> A-fragment conversion is 8x cvt_pk_bf16 + 8x
// shfl_xor(32) + half-selects per S-tile (T12 pattern).
// Lane mapping (m74/m101-verified): A row=l&31,k=8h+e; B col=l&31,k=8h+e;
// C col=l&31, row=(r&3)+8*(r>>2)+4h  (h=l>>5).
__global__ __launch_bounds__(128) void k_attn(const uint16_t* __restrict__ Qg,
                                              const uint16_t* __restrict__ Kg,
                                              const uint16_t* __restrict__ Vtg,
                                              uint16_t* __restrict__ AOg) {
    __shared__ uint16_t Klds[2][64 * 128];           // 16 KB each, XOR-swizzled
    __shared__ uint16_t Vlds[2][128 * 64];           // 16 KB each, XOR-swizzled

    const int bx = blockIdx.x;
    const int h  = bx & 15;
    const int t4 = (bx >> 4) & 15;
    const int qt = (bx < 256) ? (31 - t4) : t4;      // heavy/light CU pairing
    const int q0 = qt * 64;
    const int tid = threadIdx.x;
    const int l = tid & 63, w = tid >> 6;
    const int c31 = l & 31, hh = l >> 5;             // col lane, k/d half
    const int qw = q0 + 32 * w;                      // this wave's q base
    const size_t headTD = (size_t)h * (2048 * 128);
    const uint16_t* Kh = Kg + headTD;
    const uint16_t* Vh = Vtg + headTD;

    // Q in registers: B-frag t covers d in [16t,16t+16): elem e = Q[q=c31][16t+8h+e]
    bf16x8 qB[8];
    {
        const uint16_t* qp = Qg + headTD + (size_t)(qw + c31) * 128 + hh * 8;
#pragma unroll
        for (int t = 0; t < 8; ++t) qB[t] = *(const bf16x8*)(qp + t * 16);
    }

    f32x16 acc[4];                                   // O[32q][dt*32+c31], dt=0..3
#pragma unroll
    for (int dt = 0; dt < 4; ++dt)
#pragma unroll
        for (int r = 0; r < 16; ++r) acc[dt][r] = 0.f;
    float mrun = -1e30f, lrun = 0.f;                 // row q = qw + c31 (k-half per lane)

    const float SL2E = 0.08838834764831845f * 1.4426950408889634f; // scale*log2e
    const int   swz  = (c31 & 7) << 4;               // read swizzle (row ≡ c31 mod 8)

    auto STAGE = [&](int buf, int k0) {
#pragma unroll
        for (int p = 0; p < 8; ++p) {                // K: 64x128 rows of 256B
            int u = p * 128 + tid;                   // 16B chunk id (1024 total)
            int row = u >> 4;
            int c16 = (u & 15) ^ (row & 7);          // inverse swizzle on SOURCE
            gload_lds16(Kh + (size_t)(k0 + row) * 128 + c16 * 8,
                        (char*)&Klds[buf][0] + u * 16);
        }
#pragma unroll
        for (int p = 0; p < 8; ++p) {                // V: 128x64 rows of 128B
            int u = p * 128 + tid;
            int d = u >> 3;
            int c8 = (u & 7) ^ (d & 7);
            gload_lds16(Vh + (size_t)d * 2048 + k0 + c8 * 8,
                        (char*)&Vlds[buf][0] + u * 16);
        }
    };

    STAGE(0, 0);                                     // prologue

    for (int kt = 0; kt <= qt; ++kt) {
        asm volatile("s_waitcnt vmcnt(0)" ::: "memory"); // tile kt's loads done
        __builtin_amdgcn_s_barrier();
        __builtin_amdgcn_sched_barrier(0);
        if (kt < qt) STAGE((kt + 1) & 1, (kt + 1) * 64); // async prefetch

        const char* Kb = (const char*)&Klds[kt & 1][0];
        const char* Vb = (const char*)&Vlds[kt & 1][0];

        // ---- S^T = K Q^T : st[s] covers k in [32s,32s+32), q col = qw+c31 --
        f32x16 st[2];
        __builtin_amdgcn_s_setprio(1);
#pragma unroll
        for (int s = 0; s < 2; ++s) {
            f32x16 a;
#pragma unroll
            for (int r = 0; r < 16; ++r) a[r] = 0.f;
#pragma unroll
            for (int t = 0; t < 8; ++t) {
                int kb = (s * 32 + c31) * 256 + ((t * 32 + hh * 16) ^ swz);
                bf16x8 kf = *(const bf16x8*)(Kb + kb);
                a = __builtin_amdgcn_mfma_f32_32x32x16_bf16(kf, qB[t], a, 0, 0, 0);
            }
            st[s] = a;
        }
        __builtin_amdgcn_s_setprio(0);

        if (kt == qt) {                              // causal mask, diagonal tile
            int qg = qw + c31;
#pragma unroll
            for (int s = 0; s < 2; ++s)
#pragma unroll
                for (int r = 0; r < 16; ++r) {
                    int kg = 64 * kt + 32 * s + 4 * hh + (r & 3) + 8 * (r >> 2);
                    if (kg > qg) st[s][r] = -1e30f;
                }
        }

        // ---- defer-max online softmax (lane-local; q = qw+c31) ------------
        float pml = st[0][0];
#pragma unroll
        for (int s = 0; s < 2; ++s)
#pragma unroll
            for (int r = 0; r < 16; ++r) pml = fmaxf(pml, st[s][r]);

        if (!__all(pml * SL2E <= mrun + 11.f)) {     // rare: true max + rescale
            float mx = fmaxf(pml, __shfl_xor(pml, 32, 64)); // join k-halves
            float mn = fmaxf(mrun, mx * SL2E);
            float corr = exp2f(mrun - mn);
            mrun = mn;
            lrun *= corr;
            float ca[16];
#pragma unroll
            for (int r = 0; r < 16; ++r)             // corr for acc row q_acc(r)
                ca[r] = __shfl(corr, (r & 3) + 8 * (r >> 2) + 4 * hh, 64);
#pragma unroll
            for (int dt = 0; dt < 4; ++dt)
#pragma unroll
                for (int r = 0; r < 16; ++r) acc[dt][r] *= ca[r];
        }

        // ---- P = exp2(S*SL2E - mrun); pack to bf16; exchange lane halves --
        bf16x8 paf[4];                               // A-frags for PV k-tiles 0..3
        float psum = 0.f;
#pragma unroll
        for (int s = 0; s < 2; ++s) {
            float p[16];
#pragma unroll
            for (int r = 0; r < 16; ++r) {
                p[r] = exp2f(fmaf(st[s][r], SL2E, -mrun));
                psum += p[r];
            }
            uint32_t W[8], X[8];
#pragma unroll
            for (int i = 0; i < 8; ++i)
                asm("v_cvt_pk_bf16_f32 %0, %1, %2"
                    : "=v"(W[i]) : "v"(p[2 * i]), "v"(p[2 * i + 1]));
#pragma unroll
            for (int i = 0; i < 8; ++i) X[i] = __shfl_xor(W[i], 32, 64);
            // frag j=2s   : k = 16*(2s)   + 8h + e
            // frag j=2s+1 : k = 16*(2s+1) + 8h + e
            union { uint32_t u[4]; bf16x8 v; } fa, fb;
            fa.u[0] = hh ? X[2] : W[0];  fa.u[1] = hh ? X[3] : W[1];
            fa.u[2] = hh ? W[2] : X[0];  fa.u[3] = hh ? W[3] : X[1];
            fb.u[0] = hh ? X[6] : W[4];  fb.u[1] = hh ? X[7] : W[5];
            fb.u[2] = hh ? W[6] : X[4];  fb.u[3] = hh ? W[7] : X[5];
            paf[2 * s]     = fa.v;
            paf[2 * s + 1] = fb.v;
        }
        lrun += psum;

        // ---- O += P V : A=P[32q][16k], B=V[16k][32d] -----------------------
        __builtin_amdgcn_s_setprio(1);
#pragma unroll
        for (int j = 0; j < 4; ++j)
#pragma unroll
            for (int dt = 0; dt < 4; ++dt) {
                int vb = (dt * 32 + c31) * 128 + ((j * 32 + hh * 16) ^ swz);
                bf16x8 vf = *(const bf16x8*)(Vb + vb);
                acc[dt] = __builtin_amdgcn_mfma_f32_32x32x16_bf16(paf[j], vf, acc[dt], 0, 0, 0);
            }
        __builtin_amdgcn_s_setprio(0);
    }

    // ---- epilogue: join k-halves, redistribute 1/lsum to acc rows ---------
    float lsum = lrun + __shfl_xor(lrun, 32, 64);
    float linv = 1.f / lsum;
    float inv[16];
#pragma unroll
    for (int r = 0; r < 16; ++r)
        inv[r] = __shfl(linv, (r & 3) + 8 * (r >> 2) + 4 * hh, 64);
    const int b = h >> 3, n = h & 7;
#pragma unroll
    for (int dt = 0; dt < 4; ++dt)
#pragma unroll
        for (int r = 0; r < 16; ++r) {
            int trow = qw + (r & 3) + 8 * (r >> 2) + 4 * hh;
            AOg[((size_t)(b * 2048 + trow)) * 1024 + n * 128 + dt * 32 + c31] =
                f2bf(acc[dt][r] * inv[r]);
        }
}

// ------------------------------------------------------- blade mixing epilogue
__global__ __launch_bounds__(256) void k_mix(const float* __restrict__ out,
                                             const float* __restrict__ alpha,
                                             float* __restrict__ fin) {
    constexpr int SI[42] = {1,1,1,1,1,1, 2,2,2,2,2,2, 3,3,3,3,3,3, 4,4,4,4,4,4,
                            5,5,5,5,5,5, 6,6,6,6,6,6, 7,7,7,7,7,7};
    constexpr int SJ[42] = {2,3,4,5,6,7, 1,3,4,5,6,7, 1,2,4,5,6,7, 1,2,3,5,6,7,
                            1,2,3,4,6,7, 1,2,3,4,5,7, 1,2,3,4,5,6};
    constexpr int TG[42] = {4,5,2,3,7,6, 4,6,1,7,3,5, 5,6,7,1,2,4, 2,1,7,6,5,3,
                            3,7,1,6,4,2, 7,3,2,5,4,1, 6,5,4,3,2,1};
    constexpr float SG[42] = {+1,+1,+1,+1,+1,+1, -1,+1,-1,-1,+1,-1, -1,-1,+1,-1,-1,+1,
                              -1,+1,+1,-1,+1,-1, -1,-1,+1,+1,-1,+1, +1,-1,+1,-1,+1,-1,
                              +1,-1,+1,-1,+1,-1};
    int idx = blockIdx.x * 256 + threadIdx.x;        // B*T * D
    int d = idx & 127, bt = idx >> 7;
    size_t base = (size_t)bt * 1024 + d;
    float o[8], r[8];
#pragma unroll
    for (int hh = 0; hh < 8; ++hh) { o[hh] = out[base + hh * 128]; r[hh] = o[hh]; }
#pragma unroll
    for (int p = 0; p < 42; ++p)
        r[TG[p]] += alpha[SI[p] * 8 + SJ[p]] * SG[p] * o[SI[p]] * o[SJ[p]];
#pragma unroll
    for (int hh = 0; hh < 8; ++hh) fin[base + hh * 128] = r[hh];
}

// ---------------------------------------------------------------------------
extern "C" void kernel_launch(void* const* d_in, const int* in_sizes, int n_in,
                              void* d_out, int out_size, void* d_ws, size_t ws_size,
                              hipStream_t stream) {
    (void)in_sizes; (void)n_in; (void)out_size; (void)ws_size;
    const float* mv    = (const float*)d_in[0];
    const float* Wqkv  = (const float*)d_in[1];
    const float* Wo    = (const float*)d_in[2];
    const float* alpha = (const float*)d_in[3];
    float* outp = (float*)d_out;
    char* ws = (char*)d_ws;

    // workspace layout (bytes); AO overlays Xbf, outF overlays QKV
    uint16_t* Xbf  = (uint16_t*)(ws + 0);            //  8 MB  [4096][1024]
    uint16_t* Wqt  = (uint16_t*)(ws + 8388608);      //  6 MB  [3072][1024]
    uint16_t* Wot  = (uint16_t*)(ws + 14680064);     //  2 MB  [1024][1024]
    uint16_t* QKV  = (uint16_t*)(ws + 16777216);     // 24 MB  [4096][3072]
    uint16_t* Qr   = (uint16_t*)(ws + 41943040);     //  8 MB  [16][2048][128]
    uint16_t* Kr   = (uint16_t*)(ws + 50331648);     //  8 MB
    uint16_t* Vt   = (uint16_t*)(ws + 58720256);     //  8 MB  [16][128][2048]
    float*    ctab = (float*)(ws + 67108864);        // 0.5 MB
    float*    stab = (float*)(ws + 67633152);        // 0.5 MB
    uint16_t* AO   = (uint16_t*)(ws + 0);            // overlay (X dead after GEMM1)
    float*    outF = (float*)(ws + 16777216);        // overlay (QKV dead after rope/vtrans)

    k_cast  <<<4096, 256, 0, stream>>>(mv, Xbf, 4096 * 1024);
    k_wtrans<<<dim3(48, 16), 256, 0, stream>>>(Wqkv, Wqt, 1024, 3072);
    k_wtrans<<<dim3(16, 16), 256, 0, stream>>>(Wo, Wot, 1024, 1024);
    k_tab   <<<512, 256, 0, stream>>>(ctab, stab);
    k_gemm<uint16_t><<<dim3(24, 32), 256, 0, stream>>>(Xbf, Wqt, QKV, 4096, 3072, 1024);
    k_rope  <<<8192, 256, 0, stream>>>(QKV, ctab, stab, Qr, Kr);
    k_vtrans<<<dim3(2, 32, 16), 256, 0, stream>>>(QKV, Vt);
    k_attn  <<<512, 128, 0, stream>>>(Qr, Kr, Vt, AO);
    k_gemm<float><<<dim3(8, 32), 256, 0, stream>>>(AO, Wot, outF, 4096, 1024, 1024);
    k_mix   <<<2048, 256, 0, stream>>>(outF, alpha, outp);
}

// Round 5
// 155.839 us; speedup vs baseline: 1.0720x; 1.0720x over previous
//
#include <hip/hip_runtime.h>
#include <stdint.h>

// ---------------------------------------------------------------------------
// GeometricAttention: x@Wqkv -> RoPE -> causal MHA -> @Wo -> blade mixing
// B=2 T=2048 N=8 D=128, d_model=1024. bf16 MFMA pipeline, fp32 accum.
// ---------------------------------------------------------------------------

typedef __attribute__((ext_vector_type(8)))  __bf16 bf16x8;
typedef __attribute__((ext_vector_type(4)))  float  f32x4;
typedef __attribute__((ext_vector_type(16))) float  f32x16;

__device__ __forceinline__ uint16_t f2bf(float f) {
    uint32_t u = __float_as_uint(f);
    u += 0x7FFFu + ((u >> 16) & 1u);           // RNE
    return (uint16_t)(u >> 16);
}
__device__ __forceinline__ float bf2f(uint16_t h) {
    return __uint_as_float(((uint32_t)h) << 16);
}

__device__ __forceinline__ void gload_lds16(const void* g, void* l) {
    __builtin_amdgcn_global_load_lds(
        (__attribute__((address_space(1))) void*)g,
        (__attribute__((address_space(3))) void*)l, 16, 0, 0);
}

__device__ __forceinline__ void store_out(uint16_t* p, float v) { *p = f2bf(v); }
__device__ __forceinline__ void store_out(float* p, float v)    { *p = v; }

// ---------------------------------------------------------------- cast fp32->bf16
__global__ __launch_bounds__(256) void k_cast(const float* __restrict__ in,
                                              uint16_t* __restrict__ out, int n) {
    int i = blockIdx.x * 256 + threadIdx.x;          // one float4 per thread
    if (i * 4 >= n) return;
    float4 v = ((const float4*)in)[i];
    ushort4 o = make_ushort4(f2bf(v.x), f2bf(v.y), f2bf(v.z), f2bf(v.w));
    ((ushort4*)out)[i] = o;
}

// ------------------------------------------------- transpose W [K][N] -> Wt [N][K] bf16
__global__ __launch_bounds__(256) void k_wtrans(const float* __restrict__ W,
                                                uint16_t* __restrict__ Wt,
                                                int K, int N) {
    __shared__ uint16_t tile[64][65];
    const int k0 = blockIdx.y * 64, n0 = blockIdx.x * 64;
    const int c = threadIdx.x & 63, r4 = threadIdx.x >> 6;
#pragma unroll
    for (int i = 0; i < 16; ++i) {
        int r = r4 + i * 4;
        tile[r][c] = f2bf(W[(size_t)(k0 + r) * N + n0 + c]);
    }
    __syncthreads();
#pragma unroll
    for (int i = 0; i < 16; ++i) {
        int r = r4 + i * 4;
        Wt[(size_t)(n0 + r) * K + k0 + c] = tile[c][r];
    }
}

// ---------------------------------------------------------------- RoPE tables
__global__ __launch_bounds__(256) void k_tab(float* __restrict__ ct,
                                             float* __restrict__ st) {
    int i = blockIdx.x * 256 + threadIdx.x;          // 2048*64
    int t = i >> 6, f = i & 63;
    float inv = expf(-(float)f * 0.14391156830441f); // ln(10000)/64
    float ang = (float)t * inv;
    ct[i] = cosf(ang);
    st[i] = sinf(ang);
}

// ------------------------------------------------------- m97-style bf16 GEMM
// C[M][N] = A[M][K] * Bt[N][K]^T ; 128x128 tile, BK=32, 4 waves
template <typename OutT>
__global__ __launch_bounds__(256) void k_gemm(const uint16_t* __restrict__ A,
                                              const uint16_t* __restrict__ Bt,
                                              OutT* __restrict__ C,
                                              int M, int N, int K) {
    __shared__ uint16_t Atile[128 * 32];
    __shared__ uint16_t Btile[128 * 32];
    const int m0 = blockIdx.y << 7, n0 = blockIdx.x << 7;
    const int tid = threadIdx.x;
    const int l = tid & 63, w = tid >> 6;
    const int lr = l & 15, lg = l >> 4;
    const int wm = (w >> 1) << 6, wn = (w & 1) << 6;

    f32x4 acc[4][4];
#pragma unroll
    for (int i = 0; i < 4; ++i)
#pragma unroll
        for (int j = 0; j < 4; ++j) acc[i][j] = (f32x4){0.f, 0.f, 0.f, 0.f};

    const int nk = K >> 5;
    for (int kt = 0; kt < nk; ++kt) {
        const int k0 = kt << 5;
        __syncthreads();
#pragma unroll
        for (int c = 0; c < 4; ++c) {
            int idx = c * 256 + tid;                 // 0..1023, wave-contiguous
            if (idx < 512) {
                int r = idx >> 2, kc = (idx & 3) << 3;
                gload_lds16(A + (size_t)(m0 + r) * K + k0 + kc, &Atile[idx * 8]);
            } else {
                int i2 = idx - 512;
                int r = i2 >> 2, kc = (i2 & 3) << 3;
                gload_lds16(Bt + (size_t)(n0 + r) * K + k0 + kc, &Btile[i2 * 8]);
            }
        }
        __syncthreads();
        bf16x8 af[4], bfv[4];
#pragma unroll
        for (int i = 0; i < 4; ++i) {
            af[i]  = *(const bf16x8*)(&Atile[(wm + i * 16 + lr) * 32 + lg * 8]);
            bfv[i] = *(const bf16x8*)(&Btile[(wn + i * 16 + lr) * 32 + lg * 8]);
        }
#pragma unroll
        for (int mi = 0; mi < 4; ++mi)
#pragma unroll
            for (int ni = 0; ni < 4; ++ni)
                acc[mi][ni] = __builtin_amdgcn_mfma_f32_16x16x32_bf16(
                    af[mi], bfv[ni], acc[mi][ni], 0, 0, 0);
    }
    // C/D layout: col = lane&15, row = (lane>>4)*4 + reg   [m89-verified]
#pragma unroll
    for (int mi = 0; mi < 4; ++mi)
#pragma unroll
        for (int ni = 0; ni < 4; ++ni)
#pragma unroll
            for (int r = 0; r < 4; ++r) {
                int row = m0 + wm + mi * 16 + lg * 4 + r;
                int col = n0 + wn + ni * 16 + lr;
                store_out(&C[(size_t)row * N + col], acc[mi][ni][r]);
            }
}

// ------------------------------------------- RoPE apply: QKV -> Q,K [h][T][D]
__global__ __launch_bounds__(256) void k_rope(const uint16_t* __restrict__ qkv,
                                              const float* __restrict__ ct,
                                              const float* __restrict__ st,
                                              uint16_t* __restrict__ Qo,
                                              uint16_t* __restrict__ Ko) {
    int idx = blockIdx.x * 256 + threadIdx.x;        // B*T*N*64 pairs
    int d  = idx & 63;
    int n  = (idx >> 6) & 7;
    int bt = idx >> 9;
    int t  = bt & 2047, b = bt >> 11;
    float c = ct[t * 64 + d], s = st[t * 64 + d];
    size_t base = (size_t)bt * 3072 + n * 128 + d;
    float q1 = bf2f(qkv[base]),        q2 = bf2f(qkv[base + 64]);
    float k1 = bf2f(qkv[base + 1024]), k2 = bf2f(qkv[base + 1024 + 64]);
    size_t ob = ((size_t)(b * 8 + n) * 2048 + t) * 128 + d;
    Qo[ob]      = f2bf(q1 * c - q2 * s);
    Qo[ob + 64] = f2bf(q2 * c + q1 * s);
    Ko[ob]      = f2bf(k1 * c - k2 * s);
    Ko[ob + 64] = f2bf(k2 * c + k1 * s);
}

// -------------------------------------- V transpose: QKV v-part -> Vt [h][D][T]
__global__ __launch_bounds__(256) void k_vtrans(const uint16_t* __restrict__ qkv,
                                                uint16_t* __restrict__ Vt) {
    __shared__ uint16_t tile[64][65];
    const int h = blockIdx.z, b = h >> 3, n = h & 7;
    const int t0 = blockIdx.y * 64, d0 = blockIdx.x * 64;
    const int c = threadIdx.x & 63, r4 = threadIdx.x >> 6;
#pragma unroll
    for (int i = 0; i < 16; ++i) {
        int r = r4 + i * 4;                          // t offset
        tile[r][c] = qkv[(size_t)(b * 2048 + t0 + r) * 3072 + 2048 + n * 128 + d0 + c];
    }
    __syncthreads();
#pragma unroll
    for (int i = 0; i < 16; ++i) {
        int r = r4 + i * 4;                          // d offset
        Vt[((size_t)h * 128 + d0 + r) * 2048 + t0 + c] = tile[c][r];
    }
}

// --------------------------------------------------- causal flash attention
// R5: 4 waves = 2 q-groups(32 rows) x 2 k-parities, KVBLK=32, QW=32.
// K never touches LDS (direct global->reg A-frags, double-buffered 1 tile
// ahead). V staged in an 8-slot LDS ring via global_load_lds (linear dest,
// inverse-swizzled source), 2 pairs ahead. Deferred-PV pipeline: per body
// {barrier; PV(prev); QK(cur) — K-wait hides under PV; softmax->paf in regs;
// issue K(next); stage V(+2)}. Parity partials merged at end via LDS.
// Lane maps (m74/m101): A row=l&31,k=8h+e; B col=l&31; C col=l&31,
// row=(r&3)+8(r>>2)+4h.
__global__ __launch_bounds__(256, 2) void k_attn(const uint16_t* __restrict__ Qg,
                                                 const uint16_t* __restrict__ Kg,
                                                 const uint16_t* __restrict__ Vtg,
                                                 uint16_t* __restrict__ AOg) {
    __shared__ char  Vring[8 * 8192];                // 8 V tiles (32k x 128d each)
    __shared__ float mlbuf[2][2][32];

    const int bx = blockIdx.x;
    const int h  = bx & 15;
    const int t4 = (bx >> 4) & 15;
    const int qt = (bx < 256) ? (31 - t4) : t4;      // heavy/light CU pairing
    const int q0 = qt * 64;
    const int tid = threadIdx.x;
    const int l = tid & 63, w = tid >> 6;
    const int g = w & 1, par = w >> 1;               // q-group, k-parity
    const int c31 = l & 31, hh = l >> 5;
    const int lastT = 2 * qt + g;                    // last k-tile this q-group needs
    const size_t headTD = (size_t)h * (2048 * 128);
    const uint16_t* Kh = Kg + headTD;
    const uint16_t* Vh = Vtg + headTD;

    // Q in registers: B-frag col=q=c31, contraction d = 16t + 8hh + e
    bf16x8 qB[8];
    {
        const uint16_t* qp = Qg + headTD + (size_t)(q0 + 32 * g + c31) * 128 + hh * 8;
#pragma unroll
        for (int t = 0; t < 8; ++t) qB[t] = *(const bf16x8*)(qp + t * 16);
    }

    f32x16 acc[4];                                   // O[q-rows][dt*32+c31]
#pragma unroll
    for (int dt = 0; dt < 4; ++dt)
#pragma unroll
        for (int r = 0; r < 16; ++r) acc[dt][r] = 0.f;
    float mrun = -1e30f, lrun = 0.f;                 // per-lane row q = c31 (hh-split sums)
    bf16x8 paf[2];

    const float SL2E = 0.08838834764831845f * 1.4426950408889634f; // scale*log2e

    auto LOADK = [&](bf16x8* d, int t) {             // A-frags: K[t*32+c31][16i+8hh+e]
        const uint16_t* kp = Kh + (size_t)(t * 32 + c31) * 128 + hh * 8;
#pragma unroll
        for (int i = 0; i < 8; ++i) d[i] = *(const bf16x8*)(kp + i * 16);
    };
    auto STAGEPAIR = [&](int pp) {                   // stage V tiles 2pp, 2pp+1
#pragma unroll
        for (int i = 0; i < 4; ++i) {
            int u2 = i * 256 + tid;
            int tt = 2 * pp + (u2 >> 9);
            int uu = u2 & 511;
            int d  = uu >> 2, c16 = uu & 3;
            gload_lds16(Vh + (size_t)d * 2048 + tt * 32 + (c16 ^ ((d >> 1) & 3)) * 8,
                        Vring + (tt & 7) * 8192 + d * 64 + c16 * 16);
        }
    };
    auto PV = [&](int t) {                           // O += P V for tile t
        const char* Vb = Vring + (t & 7) * 8192;
        __builtin_amdgcn_s_setprio(1);
#pragma unroll
        for (int j = 0; j < 2; ++j)
#pragma unroll
            for (int dt = 0; dt < 4; ++dt) {
                int dr = dt * 32 + c31;
                bf16x8 vf = *(const bf16x8*)(Vb + dr * 64 +
                             ((j * 32 + hh * 16) ^ (((dr >> 1) & 3) << 4)));
                acc[dt] = __builtin_amdgcn_mfma_f32_32x32x16_bf16(paf[j], vf, acc[dt], 0, 0, 0);
            }
        __builtin_amdgcn_s_setprio(0);
    };
    auto BODY = [&](int p, bf16x8* kc, bf16x8* kn) {
        __builtin_amdgcn_s_barrier();
        if (p > 0) PV(2 * (p - 1) + par);            // deferred PV (prev tile)
        const int t = 2 * p + par;
        if (t <= lastT) {
            // S^T = K Q^T : lane (c31=q, hh); k(r) = (r&3)+8(r>>2)+4hh
            f32x16 s;
#pragma unroll
            for (int r = 0; r < 16; ++r) s[r] = 0.f;
            __builtin_amdgcn_s_setprio(1);
#pragma unroll
            for (int i = 0; i < 8; ++i)
                s = __builtin_amdgcn_mfma_f32_32x32x16_bf16(kc[i], qB[i], s, 0, 0, 0);
            __builtin_amdgcn_s_setprio(0);
            if (t == lastT) {                        // diagonal tile mask
#pragma unroll
                for (int r = 0; r < 16; ++r)
                    if ((r & 3) + 8 * (r >> 2) + 4 * hh > c31) s[r] = -1e30f;
            }
            float pml = s[0];
#pragma unroll
            for (int r = 1; r < 16; ++r) pml = fmaxf(pml, s[r]);
            if (!__all(pml * SL2E <= mrun + 11.f)) { // rare: true max + rescale
                float mx = fmaxf(pml, __shfl_xor(pml, 32, 64));
                float mn = fmaxf(mrun, mx * SL2E);
                float corr = exp2f(mrun - mn);
                mrun = mn;
                lrun *= corr;
#pragma unroll
                for (int dt = 0; dt < 4; ++dt)
#pragma unroll
                    for (int r = 0; r < 16; ++r) {
                        float cr = __shfl(corr, (r & 3) + 8 * (r >> 2) + 4 * hh, 64);
                        acc[dt][r] *= cr;
                    }
            }
            float p_[16], psum = 0.f;
#pragma unroll
            for (int r = 0; r < 16; ++r) {
                p_[r] = exp2f(fmaf(s[r], SL2E, -mrun));
                psum += p_[r];
            }
            lrun += psum;
            uint32_t W[8], X[8];
#pragma unroll
            for (int i = 0; i < 8; ++i)
                asm("v_cvt_pk_bf16_f32 %0, %1, %2"
                    : "=v"(W[i]) : "v"(p_[2 * i]), "v"(p_[2 * i + 1]));
#pragma unroll
            for (int i = 0; i < 8; ++i) X[i] = __shfl_xor(W[i], 32, 64);
            union { uint32_t u[4]; bf16x8 v; } fa, fb;
            fa.u[0] = hh ? X[2] : W[0];  fa.u[1] = hh ? X[3] : W[1];
            fa.u[2] = hh ? W[2] : X[0];  fa.u[3] = hh ? W[3] : X[1];
            fb.u[0] = hh ? X[6] : W[4];  fb.u[1] = hh ? X[7] : W[5];
            fb.u[2] = hh ? W[6] : X[4];  fb.u[3] = hh ? W[7] : X[5];
            paf[0] = fa.v;
            paf[1] = fb.v;
        }
        if (p + 1 <= qt) LOADK(kn, 2 * (p + 1) + par);
        if (p + 2 <= qt) STAGEPAIR(p + 2);
    };

    // prologue: V(0) first so body-0's K-wait drains it; K before V(1)
    STAGEPAIR(0);
    bf16x8 kR0[8], kR1[8];
    LOADK(kR0, par);
    if (qt >= 1) STAGEPAIR(1);

    int p = 0;
    for (;;) {
        BODY(p, kR0, kR1);
        if (++p > qt) break;
        BODY(p, kR1, kR0);
        if (++p > qt) break;
    }

    // epilogue: drain all staging (skipped-QK waves never waited), final PV
    asm volatile("s_waitcnt vmcnt(0)" ::: "memory");
    __syncthreads();
    if (2 * qt + par <= lastT) PV(2 * qt + par);     // all waves except g0/par1
    __syncthreads();

    float* mb = (float*)Vring;                       // merge buffer overlay
    if (par == 1) {
        float lf = lrun + __shfl_xor(lrun, 32, 64);
#pragma unroll
        for (int dt = 0; dt < 4; ++dt)
#pragma unroll
            for (int r = 0; r < 16; ++r)
                mb[((g * 4 + dt) * 16 + r) * 64 + l] = acc[dt][r];
        if (hh == 0) { mlbuf[g][0][c31] = mrun; mlbuf[g][1][c31] = lf; }
    }
    __syncthreads();
    if (par == 0) {
        float l0 = lrun + __shfl_xor(lrun, 32, 64);
        float m1 = mlbuf[g][0][c31], l1 = mlbuf[g][1][c31];
        float m12 = fmaxf(mrun, m1);
        float f0 = exp2f(mrun - m12);
        float f1 = exp2f(m1 - m12);
        float linv = 1.f / (l0 * f0 + l1 * f1);
        float v0 = f0 * linv, v1 = f1 * linv;
        const int b = h >> 3, n = h & 7;
#pragma unroll
        for (int dt = 0; dt < 4; ++dt)
#pragma unroll
            for (int r = 0; r < 16; ++r) {
                int qr = (r & 3) + 8 * (r >> 2) + 4 * hh;
                float a0 = __shfl(v0, qr, 64), a1 = __shfl(v1, qr, 64);
                float o = acc[dt][r] * a0 + mb[((g * 4 + dt) * 16 + r) * 64 + l] * a1;
                AOg[((size_t)(b * 2048 + q0 + 32 * g + qr)) * 1024 + n * 128 + dt * 32 + c31]
                    = f2bf(o);
            }
    }
}

// ------------------------------------------------------- blade mixing epilogue
__global__ __launch_bounds__(256) void k_mix(const float* __restrict__ out,
                                             const float* __restrict__ alpha,
                                             float* __restrict__ fin) {
    constexpr int SI[42] = {1,1,1,1,1,1, 2,2,2,2,2,2, 3,3,3,3,3,3, 4,4,4,4,4,4,
                            5,5,5,5,5,5, 6,6,6,6,6,6, 7,7,7,7,7,7};
    constexpr int SJ[42] = {2,3,4,5,6,7, 1,3,4,5,6,7, 1,2,4,5,6,7, 1,2,3,5,6,7,
                            1,2,3,4,6,7, 1,2,3,4,5,7, 1,2,3,4,5,6};
    constexpr int TG[42] = {4,5,2,3,7,6, 4,6,1,7,3,5, 5,6,7,1,2,4, 2,1,7,6,5,3,
                            3,7,1,6,4,2, 7,3,2,5,4,1, 6,5,4,3,2,1};
    constexpr float SG[42] = {+1,+1,+1,+1,+1,+1, -1,+1,-1,-1,+1,-1, -1,-1,+1,-1,-1,+1,
                              -1,+1,+1,-1,+1,-1, -1,-1,+1,+1,-1,+1, +1,-1,+1,-1,+1,-1,
                              +1,-1,+1,-1,+1,-1};
    int idx = blockIdx.x * 256 + threadIdx.x;        // B*T * D
    int d = idx & 127, bt = idx >> 7;
    size_t base = (size_t)bt * 1024 + d;
    float o[8], r[8];
#pragma unroll
    for (int hh = 0; hh < 8; ++hh) { o[hh] = out[base + hh * 128]; r[hh] = o[hh]; }
#pragma unroll
    for (int p = 0; p < 42; ++p)
        r[TG[p]] += alpha[SI[p] * 8 + SJ[p]] * SG[p] * o[SI[p]] * o[SJ[p]];
#pragma unroll
    for (int hh = 0; hh < 8; ++hh) fin[base + hh * 128] = r[hh];
}

// ---------------------------------------------------------------------------
extern "C" void kernel_launch(void* const* d_in, const int* in_sizes, int n_in,
                              void* d_out, int out_size, void* d_ws, size_t ws_size,
                              hipStream_t stream) {
    (void)in_sizes; (void)n_in; (void)out_size; (void)ws_size;
    const float* mv    = (const float*)d_in[0];
    const float* Wqkv  = (const float*)d_in[1];
    const float* Wo    = (const float*)d_in[2];
    const float* alpha = (const float*)d_in[3];
    float* outp = (float*)d_out;
    char* ws = (char*)d_ws;

    // workspace layout (bytes); AO overlays Xbf, outF overlays QKV
    uint16_t* Xbf  = (uint16_t*)(ws + 0);            //  8 MB  [4096][1024]
    uint16_t* Wqt  = (uint16_t*)(ws + 8388608);      //  6 MB  [3072][1024]
    uint16_t* Wot  = (uint16_t*)(ws + 14680064);     //  2 MB  [1024][1024]
    uint16_t* QKV  = (uint16_t*)(ws + 16777216);     // 24 MB  [4096][3072]
    uint16_t* Qr   = (uint16_t*)(ws + 41943040);     //  8 MB  [16][2048][128]
    uint16_t* Kr   = (uint16_t*)(ws + 50331648);     //  8 MB
    uint16_t* Vt   = (uint16_t*)(ws + 58720256);     //  8 MB  [16][128][2048]
    float*    ctab = (float*)(ws + 67108864);        // 0.5 MB
    float*    stab = (float*)(ws + 67633152);        // 0.5 MB
    uint16_t* AO   = (uint16_t*)(ws + 0);            // overlay (X dead after GEMM1)
    float*    outF = (float*)(ws + 16777216);        // overlay (QKV dead after rope/vtrans)

    k_cast  <<<4096, 256, 0, stream>>>(mv, Xbf, 4096 * 1024);
    k_wtrans<<<dim3(48, 16), 256, 0, stream>>>(Wqkv, Wqt, 1024, 3072);
    k_wtrans<<<dim3(16, 16), 256, 0, stream>>>(Wo, Wot, 1024, 1024);
    k_tab   <<<512, 256, 0, stream>>>(ctab, stab);
    k_gemm<uint16_t><<<dim3(24, 32), 256, 0, stream>>>(Xbf, Wqt, QKV, 4096, 3072, 1024);
    k_rope  <<<8192, 256, 0, stream>>>(QKV, ctab, stab, Qr, Kr);
    k_vtrans<<<dim3(2, 32, 16), 256, 0, stream>>>(QKV, Vt);
    k_attn  <<<512, 256, 0, stream>>>(Qr, Kr, Vt, AO);
    k_gemm<float><<<dim3(8, 32), 256, 0, stream>>>(AO, Wot, outF, 4096, 1024, 1024);
    k_mix   <<<2048, 256, 0, stream>>>(outF, alpha, outp);
}